// Round 2
// baseline (5613.411 us; speedup 1.0000x reference)
//
#include <hip/hip_runtime.h>

typedef unsigned short u16;
typedef unsigned int u32;

#define DIM 768
#define QKV3 2304
#define SEQ 1024
#define SCALE 0.14433756729740643f  // 48^-0.5

__device__ __forceinline__ float bflo(u32 u) { return __uint_as_float(u << 16); }
__device__ __forceinline__ float bfhi(u32 u) { return __uint_as_float(u & 0xffff0000u); }
__device__ __forceinline__ float bfs(u16 h) { return __uint_as_float(((u32)h) << 16); }
__device__ __forceinline__ u16 f2bf(float f) {
  u32 u = __float_as_uint(f);
  return (u16)((u + 0x7fffu + ((u >> 16) & 1u)) >> 16);  // RNE
}

// load 4 consecutive elements as float
__device__ __forceinline__ void load4(const float* p, float* d) {
  float4 v = *(const float4*)p;
  d[0] = v.x; d[1] = v.y; d[2] = v.z; d[3] = v.w;
}
__device__ __forceinline__ void load4(const u16* p, float* d) {
  const u32* q = (const u32*)p;
  u32 a = q[0], b = q[1];
  d[0] = bflo(a); d[1] = bfhi(a); d[2] = bflo(b); d[3] = bfhi(b);
}
__device__ __forceinline__ void store1(u16* p, float v) { *p = f2bf(v); }
__device__ __forceinline__ void store1(float* p, float v) { *p = v; }

// ---------------- GEMM: C[M][N] = A[M][K] @ W[N][K]^T + bias[N], fp32 acc
template <typename TA, typename TW, typename TO>
__global__ __launch_bounds__(256)
void gemm_bias_kernel(const TA* __restrict__ A, const TW* __restrict__ W,
                      const float* __restrict__ bias, TO* __restrict__ C,
                      int M, int N, int K) {
  __shared__ float As[32][65];  // [k][m], padded
  __shared__ float Ws[32][65];  // [k][n], padded
  const int tid = threadIdx.x;
  const int tx = tid & 15;
  const int ty = tid >> 4;
  const int row0 = blockIdx.y * 64;
  const int col0 = blockIdx.x * 64;
  float acc[4][4];
#pragma unroll
  for (int i = 0; i < 4; ++i)
#pragma unroll
    for (int j = 0; j < 4; ++j) acc[i][j] = 0.f;

  for (int k0 = 0; k0 < K; k0 += 32) {
#pragma unroll
    for (int j = 0; j < 2; ++j) {
      int i = tid + j * 256;
      int k4 = (i & 7) * 4;
      int r = i >> 3;
      float av[4], wv[4];
      load4(A + (size_t)(row0 + r) * K + (k0 + k4), av);
      load4(W + (size_t)(col0 + r) * K + (k0 + k4), wv);
#pragma unroll
      for (int t = 0; t < 4; ++t) { As[k4 + t][r] = av[t]; Ws[k4 + t][r] = wv[t]; }
    }
    __syncthreads();
#pragma unroll
    for (int kk = 0; kk < 32; ++kk) {
      float a[4], w[4];
#pragma unroll
      for (int i = 0; i < 4; ++i) a[i] = As[kk][ty + 16 * i];
#pragma unroll
      for (int j = 0; j < 4; ++j) w[j] = Ws[kk][tx + 16 * j];
#pragma unroll
      for (int i = 0; i < 4; ++i)
#pragma unroll
        for (int j = 0; j < 4; ++j) acc[i][j] = fmaf(a[i], w[j], acc[i][j]);
    }
    __syncthreads();
  }
#pragma unroll
  for (int j = 0; j < 4; ++j) {
    int c = col0 + tx + 16 * j;
    float bv = bias[c];
#pragma unroll
    for (int i = 0; i < 4; ++i) {
      int r = row0 + ty + 16 * i;
      store1(C + (size_t)r * N + c, acc[i][j] + bv);
    }
  }
}

// ---------------- Fused talking-heads attention ----------------
// One block = (batch b, 16-query tile). Two passes over keys:
//  pass 1: S=Q.K^T*scale, L=mix1(S)+b_l, online max/sum per (q,g) via 16-lane shuffles
//  pass 2: recompute L, P=exp(L-m)/Z, W2=mix2(P)+b_w  -> LDS -> O += W2 * V
// Thread (q = tid>>4, x = tid&15): x is key-within-chunk in compute phases, head g2 in PV.
__global__ __launch_bounds__(256)
void attn_kernel(const u16* __restrict__ qkv,   // [8192][2304] bf16
                 const float* __restrict__ wl_g, const float* __restrict__ bl_g,
                 const float* __restrict__ ww_g, const float* __restrict__ bw_g,
                 u16* __restrict__ obuf) {      // [8192][768] bf16, col = g2*48+d
  __shared__ __align__(16) u16 Qs[16 * 776];     // [q][768 + pad 8]
  __shared__ __align__(16) u16 KV[256 * 52];     // K: [h][kc][52], V: [kc][g][52]
  __shared__ __align__(16) u16 Lb[16 * 16 * 17]; // W2 staging [q][g2][16 + pad]
  __shared__ float wlS[256], wwS[256], blS[16], bwS[16];

  const int tid = threadIdx.x;
  const int b = blockIdx.x >> 6;
  const int qt = blockIdx.x & 63;
  const int q = tid >> 4;
  const int x = tid & 15;

  wlS[tid] = wl_g[tid];
  wwS[tid] = ww_g[tid];
  if (tid < 16) { blS[tid] = bl_g[tid]; bwS[tid] = bw_g[tid]; }

  {  // stage Q tile (16 rows x 768), 4 bf16 per load
    const size_t base = (size_t)(b * SEQ + qt * 16) * QKV3;
#pragma unroll
    for (int j = 0; j < 12; ++j) {
      int i = tid + j * 256;
      int row = i / 192;
      int t = i - row * 192;
      const u32* src = (const u32*)(qkv + base + (size_t)row * QKV3 + t * 4);
      u32* dst = (u32*)(Qs + row * 776 + t * 4);
      dst[0] = src[0]; dst[1] = src[1];
    }
  }
  __syncthreads();

  auto stage = [&](int k0, int coloff, bool vmode) {
    const size_t rb = (size_t)(b * SEQ + k0) * QKV3 + coloff;
#pragma unroll
    for (int j = 0; j < 12; ++j) {
      int i = tid + j * 256;
      int t = i % 12;
      int rem = i / 12;
      int kc = rem & 15;
      int hg = rem >> 4;
      const u32* src = (const u32*)(qkv + rb + (size_t)kc * QKV3 + hg * 48 + t * 4);
      int off = (vmode ? (kc * 16 + hg) : (hg * 16 + kc)) * 52 + t * 4;
      u32* dst = (u32*)(KV + off);
      dst[0] = src[0]; dst[1] = src[1];
    }
  };

  auto computeS = [&](float* S) {
    const u16* qb = Qs + q * 776;
#pragma unroll
    for (int h = 0; h < 16; ++h) {
      const u16* kb = KV + (h * 16 + x) * 52;
      float s = 0.f;
#pragma unroll
      for (int t = 0; t < 12; ++t) {
        const u32* qa = (const u32*)(qb + h * 48 + t * 4);
        const u32* ka = (const u32*)(kb + t * 4);
        u32 ua0 = qa[0], ua1 = qa[1], uk0 = ka[0], uk1 = ka[1];
        s = fmaf(bflo(ua0), bflo(uk0), s);
        s = fmaf(bfhi(ua0), bfhi(uk0), s);
        s = fmaf(bflo(ua1), bflo(uk1), s);
        s = fmaf(bfhi(ua1), bfhi(uk1), s);
      }
      S[h] = s * SCALE;
    }
  };

  // ---- pass 1: softmax stats (m, Z) per (q, g); all 16 lanes of a q-group hold copies
  float m[16], Z[16];
#pragma unroll
  for (int g = 0; g < 16; ++g) { m[g] = -1e30f; Z[g] = 0.f; }

  for (int k0 = 0; k0 < SEQ; k0 += 16) {
    stage(k0, DIM, false);
    __syncthreads();
    float S[16];
    computeS(S);
#pragma unroll
    for (int g = 0; g < 16; ++g) {
      float L = blS[g];
#pragma unroll
      for (int h = 0; h < 16; ++h) L = fmaf(wlS[g * 16 + h], S[h], L);
      float cm = L;
#pragma unroll
      for (int s = 1; s < 16; s <<= 1) cm = fmaxf(cm, __shfl_xor(cm, s));
      float mn = fmaxf(m[g], cm);
      float e = __expf(L - mn);
#pragma unroll
      for (int s = 1; s < 16; s <<= 1) e += __shfl_xor(e, s);
      Z[g] = Z[g] * __expf(m[g] - mn) + e;
      m[g] = mn;
    }
    __syncthreads();
  }
#pragma unroll
  for (int g = 0; g < 16; ++g) Z[g] = 1.0f / Z[g];  // Z now holds 1/Z

  // ---- pass 2: P, W2, O accumulation
  float4 O[12];
#pragma unroll
  for (int t = 0; t < 12; ++t) O[t] = make_float4(0.f, 0.f, 0.f, 0.f);

  for (int k0 = 0; k0 < SEQ; k0 += 16) {
    stage(k0, DIM, false);
    __syncthreads();
    float S[16];
    computeS(S);
    float P[16];
#pragma unroll
    for (int g = 0; g < 16; ++g) {
      float L = blS[g];
#pragma unroll
      for (int h = 0; h < 16; ++h) L = fmaf(wlS[g * 16 + h], S[h], L);
      P[g] = __expf(L - m[g]) * Z[g];
    }
#pragma unroll
    for (int g2 = 0; g2 < 16; ++g2) {
      float w2 = bwS[g2];
#pragma unroll
      for (int g = 0; g < 16; ++g) w2 = fmaf(wwS[g2 * 16 + g], P[g], w2);
      Lb[(q * 16 + g2) * 17 + x] = f2bf(w2);
    }
    __syncthreads();
    stage(k0, 2 * DIM, true);  // V overwrites K buffer
    __syncthreads();
    const u16* lb = Lb + (q * 16 + x) * 17;  // x = g2 here
#pragma unroll
    for (int kc = 0; kc < 16; ++kc) {
      float w2 = bfs(lb[kc]);
      const u16* vb = KV + (kc * 16 + x) * 52;
#pragma unroll
      for (int t = 0; t < 12; ++t) {
        const u32* va = (const u32*)(vb + t * 4);
        u32 v0 = va[0], v1 = va[1];
        O[t].x = fmaf(w2, bflo(v0), O[t].x);
        O[t].y = fmaf(w2, bfhi(v0), O[t].y);
        O[t].z = fmaf(w2, bflo(v1), O[t].z);
        O[t].w = fmaf(w2, bfhi(v1), O[t].w);
      }
    }
    __syncthreads();
  }

  {  // write O: row (b,q), col = g2*48 + d
    u16* dst = obuf + (size_t)(b * SEQ + qt * 16 + q) * DIM + x * 48;
#pragma unroll
    for (int t = 0; t < 12; ++t) {
      u32 o0 = (u32)f2bf(O[t].x) | ((u32)f2bf(O[t].y) << 16);
      u32 o1 = (u32)f2bf(O[t].z) | ((u32)f2bf(O[t].w) << 16);
      u32* dp = (u32*)(dst + t * 4);
      dp[0] = o0; dp[1] = o1;
    }
  }
}

extern "C" void kernel_launch(void* const* d_in, const int* in_sizes, int n_in,
                              void* d_out, int out_size, void* d_ws, size_t ws_size,
                              hipStream_t stream) {
  const float* x      = (const float*)d_in[0];
  const float* w_qkv  = (const float*)d_in[1];
  const float* b_qkv  = (const float*)d_in[2];
  const float* w_l    = (const float*)d_in[3];
  const float* b_l    = (const float*)d_in[4];
  const float* w_w    = (const float*)d_in[5];
  const float* b_w    = (const float*)d_in[6];
  const float* w_proj = (const float*)d_in[7];
  const float* b_proj = (const float*)d_in[8];
  float* out = (float*)d_out;

  u16* qkv_buf  = (u16*)d_ws;                       // [8192][2304] bf16
  u16* attn_buf = qkv_buf + (size_t)8192 * QKV3;    // [8192][768]  bf16
  // total ws use: 50,331,648 bytes

  // 1) QKV projection (fp32 in -> bf16 out)
  gemm_bias_kernel<float, float, u16><<<dim3(QKV3 / 64, 8192 / 64), 256, 0, stream>>>(
      x, w_qkv, b_qkv, qkv_buf, 8192, QKV3, DIM);
  // 2) fused talking-heads attention (bf16 in/out)
  attn_kernel<<<dim3(8 * 64), 256, 0, stream>>>(
      qkv_buf, w_l, b_l, w_w, b_w, attn_buf);
  // 3) output projection (bf16 A, fp32 W -> fp32 out)
  gemm_bias_kernel<u16, float, float><<<dim3(DIM / 64, 8192 / 64), 256, 0, stream>>>(
      attn_buf, w_proj, b_proj, out, 8192, DIM, DIM);
}